// Round 14
// baseline (558.761 us; speedup 1.0000x reference)
//
#include <hip/hip_runtime.h>
#include <hip/hip_bf16.h>

#define BB 2
#define LL 2048
#define DM 256
#define DI 512
#define NST 16
#define RDT 16
#define KC 4
#define NLAY 4
#define DOUT 10
#define XDIM 48            // R + 2N
#define TOK (BB*LL)        // 4096
#define EPSF 1e-5f
#define CHUNK 8
#define NCH (LL/CHUNK)     // 256

typedef __bf16 bf16x8 __attribute__((ext_vector_type(8)));
typedef __bf16 bf16x4 __attribute__((ext_vector_type(4)));
typedef float  f32x4  __attribute__((ext_vector_type(4)));

__device__ __forceinline__ float sigmoid_f(float x) { return 1.0f / (1.0f + __expf(-x)); }

// ---------------- weight cast fp32 -> bf16 (once per call) ----------------
__global__ void cast_w_kernel(const float* __restrict__ a, const float* __restrict__ b,
                              __bf16* __restrict__ ab, __bf16* __restrict__ bb,
                              int na, int nb) {
  int stride = gridDim.x * 256;
  for (int i = blockIdx.x*256 + threadIdx.x; i < na; i += stride) ab[i] = (__bf16)a[i];
  for (int i = blockIdx.x*256 + threadIdx.x; i < nb; i += stride) bb[i] = (__bf16)b[i];
}

// ------- residual add + layernorm; first layer reads embedding directly -------
__global__ void add_ln_kernel(float* __restrict__ residual, const float* __restrict__ hidden,
                              const int* __restrict__ ids, const float* __restrict__ emb,
                              const float* __restrict__ w, const float* __restrict__ bia,
                              float* __restrict__ out, __bf16* __restrict__ out_bf,
                              int first, int write32) {
  int t = blockIdx.x, d = threadIdx.x;
  __shared__ float ws8[8];
  float r;
  if (first) r = emb[ids[t]*DM + d];
  else       r = hidden[t*DM + d] + residual[t*DM + d];
  residual[t*DM + d] = r;
  float s = r;
  #pragma unroll
  for (int o = 32; o; o >>= 1) s += __shfl_down(s, o);
  if ((d & 63) == 0) ws8[d >> 6] = s;
  __syncthreads();
  float mean = (ws8[0] + ws8[1] + ws8[2] + ws8[3]) * (1.0f/DM);
  float diff = r - mean;
  float q = diff * diff;
  #pragma unroll
  for (int o = 32; o; o >>= 1) q += __shfl_down(q, o);
  if ((d & 63) == 0) ws8[4 + (d >> 6)] = q;
  __syncthreads();
  float var = (ws8[4] + ws8[5] + ws8[6] + ws8[7]) * (1.0f/DM);
  float v = diff * rsqrtf(var + EPSF) * w[d] + bia[d];
  if (write32) out[t*DM + d] = v;
  out_bf[t*DM + d] = (__bf16)v;
}

// ---------------- bf16 MFMA GEMM (in_proj): tile M=64, E=128 ----------------
// cols<512 -> xm bf16; cols>=512 -> zg = silu(z) bf16.
__global__ __launch_bounds__(256, 2) void gemm_in_bf16(const __bf16* __restrict__ A,
                                                       const __bf16* __restrict__ W,
                                                       __bf16* __restrict__ xm,
                                                       __bf16* __restrict__ zg) {
  __shared__ __bf16 As[4*64*8];
  __shared__ __bf16 Ws[8*64*8];
  const int K = DM;
  int tid = threadIdx.x;
  int lane = tid & 63, wv = tid >> 6;
  int bm = blockIdx.y * 64, be = blockIdx.x * 128;
  int ss = tid >> 6, sq = (tid >> 4) & 3, sm = tid & 15;
  f32x4 acc[8];
  #pragma unroll
  for (int et = 0; et < 8; ++et) acc[et] = (f32x4){0.f, 0.f, 0.f, 0.f};
  for (int k0 = 0; k0 < K; k0 += 32) {
    bf16x8 av = *(const bf16x8*)&A[(size_t)(bm + ss*16 + sm)*K + k0 + sq*8];
    bf16x8 w0 = *(const bf16x8*)&W[(size_t)(be + ss*16 + sm)*K + k0 + sq*8];
    bf16x8 w1 = *(const bf16x8*)&W[(size_t)(be + 64 + ss*16 + sm)*K + k0 + sq*8];
    __syncthreads();
    *(bf16x8*)&As[((ss*4 + sq)*16 + sm)*8] = av;
    *(bf16x8*)&Ws[((ss*4 + sq)*16 + sm)*8] = w0;
    *(bf16x8*)&Ws[(((4 + ss)*4 + sq)*16 + sm)*8] = w1;
    __syncthreads();
    bf16x8 af = *(const bf16x8*)&As[(wv*64 + lane)*8];
    #pragma unroll
    for (int et = 0; et < 8; ++et) {
      bf16x8 bfr = *(const bf16x8*)&Ws[(et*64 + lane)*8];
      acc[et] = __builtin_amdgcn_mfma_f32_16x16x32_bf16(af, bfr, acc[et], 0, 0, 0);
    }
  }
  int row0 = bm + wv*16 + (lane >> 4)*4;
  int colb = lane & 15;
  #pragma unroll
  for (int et = 0; et < 8; ++et) {
    int col = be + et*16 + colb;
    if (col < DI) {
      #pragma unroll
      for (int r = 0; r < 4; ++r)
        xm[(size_t)(row0 + r)*DI + col] = (__bf16)acc[et][r];
    } else {
      #pragma unroll
      for (int r = 0; r < 4; ++r) {
        float zv = acc[et][r];
        zg[(size_t)(row0 + r)*DI + col - DI] = (__bf16)(zv * sigmoid_f(zv));
      }
    }
  }
}

// ---------------- bf16 MFMA GEMM (out_proj): tile M=64, E=64, fp32 C ----------------
__global__ __launch_bounds__(256, 2) void gemm_out_bf16(const __bf16* __restrict__ A,
                                                        const __bf16* __restrict__ W,
                                                        float* __restrict__ C) {
  __shared__ __bf16 As[4*64*8];
  __shared__ __bf16 Ws[4*64*8];
  const int K = DI, E = DM;
  int tid = threadIdx.x;
  int lane = tid & 63, wv = tid >> 6;
  int bm = blockIdx.y * 64, be = blockIdx.x * 64;
  int ss = tid >> 6, sq = (tid >> 4) & 3, sm = tid & 15;
  f32x4 acc[4];
  #pragma unroll
  for (int et = 0; et < 4; ++et) acc[et] = (f32x4){0.f, 0.f, 0.f, 0.f};
  for (int k0 = 0; k0 < K; k0 += 32) {
    bf16x8 av = *(const bf16x8*)&A[(size_t)(bm + ss*16 + sm)*K + k0 + sq*8];
    bf16x8 wvv = *(const bf16x8*)&W[(size_t)(be + ss*16 + sm)*K + k0 + sq*8];
    __syncthreads();
    *(bf16x8*)&As[((ss*4 + sq)*16 + sm)*8] = av;
    *(bf16x8*)&Ws[((ss*4 + sq)*16 + sm)*8] = wvv;
    __syncthreads();
    bf16x8 af = *(const bf16x8*)&As[(wv*64 + lane)*8];
    #pragma unroll
    for (int et = 0; et < 4; ++et) {
      bf16x8 bfr = *(const bf16x8*)&Ws[(et*64 + lane)*8];
      acc[et] = __builtin_amdgcn_mfma_f32_16x16x32_bf16(af, bfr, acc[et], 0, 0, 0);
    }
  }
  int row0 = bm + wv*16 + (lane >> 4)*4;
  int col0 = be + (lane & 15);
  #pragma unroll
  for (int et = 0; et < 4; ++et)
    #pragma unroll
    for (int r = 0; r < 4; ++r)
      C[(size_t)(row0 + r)*E + col0 + et*16] = acc[et][r];
}

// ------- x_proj with inline conv+silu: M-tile 32 (128 blocks), E=48 -------
__global__ __launch_bounds__(256) void xproj_conv(const __bf16* __restrict__ xm,
                                                  const float* __restrict__ cw,
                                                  const float* __restrict__ cb,
                                                  const float* __restrict__ W,
                                                  float* __restrict__ out) {
  __shared__ float Xs[32][36];
  __shared__ float Ws[48][36];
  int tid = threadIdx.x;
  int tx = tid & 15, ty = tid >> 4;
  int e0 = tx * 3, t0 = ty * 2;
  int bm = blockIdx.x * 32;
  int xr = tid >> 3, xco = (tid & 7) * 4;       // X staging: 32 rows x 8 quads
  int we = tid >> 2, lc = (tid & 3) * 8;        // W staging: 48 rows x 32 cols
  int tt = bm + xr;
  int l = tt & (LL-1);
  float acc[2][3] = {};
  for (int k0 = 0; k0 < DI; k0 += 32) {
    int ch = k0 + xco;
    bf16x4 v0 = *(const bf16x4*)&xm[(size_t)tt*DI + ch];
    bf16x4 v1 = (l >= 1) ? *(const bf16x4*)&xm[(size_t)(tt-1)*DI + ch] : (bf16x4){0,0,0,0};
    bf16x4 v2 = (l >= 2) ? *(const bf16x4*)&xm[(size_t)(tt-2)*DI + ch] : (bf16x4){0,0,0,0};
    bf16x4 v3 = (l >= 3) ? *(const bf16x4*)&xm[(size_t)(tt-3)*DI + ch] : (bf16x4){0,0,0,0};
    float4 cbv = *(const float4*)&cb[ch];
    float xc4[4];
    #pragma unroll
    for (int j = 0; j < 4; ++j) {
      float4 cwv = *(const float4*)&cw[(ch + j)*KC];
      float cv = ((const float*)&cbv)[j];
      cv = fmaf(cwv.x, (float)v3[j], cv);
      cv = fmaf(cwv.y, (float)v2[j], cv);
      cv = fmaf(cwv.z, (float)v1[j], cv);
      cv = fmaf(cwv.w, (float)v0[j], cv);
      xc4[j] = cv * sigmoid_f(cv);
    }
    *(float4*)&Xs[xr][xco] = make_float4(xc4[0], xc4[1], xc4[2], xc4[3]);
    if (we < 48) {
      float4 w0 = *(const float4*)&W[(size_t)we*DI + k0 + lc];
      float4 w1 = *(const float4*)&W[(size_t)we*DI + k0 + lc + 4];
      *(float4*)&Ws[we][lc]     = w0;
      *(float4*)&Ws[we][lc + 4] = w1;
    }
    __syncthreads();
    #pragma unroll
    for (int kk = 0; kk < 32; kk += 4) {
      float4 xv[2], wv[3];
      #pragma unroll
      for (int i = 0; i < 2; ++i) xv[i] = *(const float4*)&Xs[t0+i][kk];
      #pragma unroll
      for (int j = 0; j < 3; ++j) wv[j] = *(const float4*)&Ws[e0+j][kk];
      #pragma unroll
      for (int i = 0; i < 2; ++i)
        #pragma unroll
        for (int j = 0; j < 3; ++j) {
          acc[i][j] = fmaf(xv[i].x, wv[j].x, acc[i][j]);
          acc[i][j] = fmaf(xv[i].y, wv[j].y, acc[i][j]);
          acc[i][j] = fmaf(xv[i].z, wv[j].z, acc[i][j]);
          acc[i][j] = fmaf(xv[i].w, wv[j].w, acc[i][j]);
        }
    }
    __syncthreads();
  }
  #pragma unroll
  for (int i = 0; i < 2; ++i)
    #pragma unroll
    for (int j = 0; j < 3; ++j)
      out[(size_t)(bm + t0 + i)*XDIM + e0 + j] = acc[i][j];
}

// ---------------- chunked selective scan, conv inline (CHUNK=8, 1024 blocks) -------
// hloc/hinit layout: ((b*NST + n)*NCH + c)*DI + d
// dA geo path: A[n] == (n+1)*A[0] (log-arange init) -> 1 exp + 15 muls; verified
// per-thread with fallback.
__global__ __launch_bounds__(256) void scan_pass1(
    const __bf16* __restrict__ xm, const float* __restrict__ xdbl,
    const float* __restrict__ cw, const float* __restrict__ cb,
    const float* __restrict__ dtw, const float* __restrict__ dtb,
    const float* __restrict__ A_log,
    float* __restrict__ hloc, float* __restrict__ dsum) {
  __shared__ __align__(16) float DB[CHUNK][32];   // [l][0:16 dt | 16:32 B]
  int bc = blockIdx.x >> 1;                       // b*NCH + c
  int d  = ((blockIdx.x & 1) << 8) + threadIdx.x;
  int b = bc >> 8, c = bc & (NCH-1);
  int t0 = b*LL + c*CHUNK;
  int tid = threadIdx.x;
  if (tid < CHUNK*8) {
    int row = tid >> 3, q = tid & 7;
    *(float4*)&DB[row][q*4] = *(const float4*)&xdbl[(size_t)(t0+row)*XDIM + q*4];
  }
  __syncthreads();
  float4 wq[4];
  #pragma unroll
  for (int i = 0; i < 4; ++i) wq[i] = *(const float4*)&dtw[(size_t)d*RDT + i*4];
  float dtbv = dtb[d];
  float4 cwv = *(const float4*)&cw[d*KC];
  float cbv = cb[d];
  float A[NST];
  #pragma unroll
  for (int n = 0; n < NST; ++n) A[n] = -__expf(A_log[d*NST + n]);
  float A0 = A[0];
  bool geo = true;
  #pragma unroll
  for (int n = 1; n < NST; ++n) {
    float ideal = A0 * (float)(n+1);
    geo = geo && (fabsf(A[n] - ideal) <= 1e-5f * fabsf(ideal));
  }
  float x1 = 0.f, x2 = 0.f, x3 = 0.f;
  if (c > 0) {
    x1 = (float)xm[(size_t)(t0-1)*DI + d];
    x2 = (float)xm[(size_t)(t0-2)*DI + d];
    x3 = (float)xm[(size_t)(t0-3)*DI + d];
  }
  float h[NST];
  #pragma unroll
  for (int n = 0; n < NST; ++n) h[n] = 0.f;
  float ds = 0.f;
  for (int l = 0; l < CHUNK; ++l) {
    float x0 = (float)xm[(size_t)(t0+l)*DI + d];
    float cv = cbv;
    cv = fmaf(cwv.x, x3, cv); cv = fmaf(cwv.y, x2, cv);
    cv = fmaf(cwv.z, x1, cv); cv = fmaf(cwv.w, x0, cv);
    float xcv = cv * sigmoid_f(cv);
    float acc = dtbv;
    #pragma unroll
    for (int i = 0; i < 4; ++i) {
      float4 a = *(const float4*)&DB[l][i*4];
      acc = fmaf(a.x, wq[i].x, acc); acc = fmaf(a.y, wq[i].y, acc);
      acc = fmaf(a.z, wq[i].z, acc); acc = fmaf(a.w, wq[i].w, acc);
    }
    float del = fmaxf(acc, 0.f) + log1pf(__expf(-fabsf(acc)));
    ds += del;
    float dx = del * xcv;
    if (geo) {
      float e = __expf(del * A0);
      float dA = e;
      h[0] = fmaf(dA, h[0], dx * DB[l][16]);
      #pragma unroll
      for (int n = 1; n < NST; ++n) {
        dA *= e;
        h[n] = fmaf(dA, h[n], dx * DB[l][16 + n]);
      }
    } else {
      #pragma unroll
      for (int n = 0; n < NST; ++n)
        h[n] = fmaf(__expf(del * A[n]), h[n], dx * DB[l][16 + n]);
    }
    x3 = x2; x2 = x1; x1 = x0;
  }
  #pragma unroll
  for (int n = 0; n < NST; ++n)
    hloc[((size_t)(b*NST + n)*NCH + c)*DI + d] = h[n];
  dsum[(size_t)bc*DI + d] = ds;
}

__global__ __launch_bounds__(256) void scan_pass2(
    const float* __restrict__ hloc, const float* __restrict__ dsum,
    const float* __restrict__ A_log, float* __restrict__ hinit) {
  int g = blockIdx.x*256 + threadIdx.x;
  int d = g & (DI-1);
  int n = (g >> 9) & (NST-1);
  int b = g >> 13;
  float A = -__expf(A_log[d*NST + n]);
  float hc = 0.f;
  size_t base = (size_t)(b*NST + n)*NCH*DI + d;
  for (int c = 0; c < NCH; ++c) {
    hinit[base + (size_t)c*DI] = hc;
    float P = __expf(A * dsum[(size_t)(b*NCH + c)*DI + d]);
    hc = fmaf(P, hc, hloc[base + (size_t)c*DI]);
  }
}

__global__ __launch_bounds__(256) void scan_pass3(
    const __bf16* __restrict__ xm, const float* __restrict__ xdbl,
    const __bf16* __restrict__ zg, const float* __restrict__ cw,
    const float* __restrict__ cb, const float* __restrict__ dtw,
    const float* __restrict__ dtb, const float* __restrict__ A_log,
    const float* __restrict__ Dp, const float* __restrict__ hinit,
    __bf16* __restrict__ y) {
  __shared__ __align__(16) float DBC[CHUNK][48];  // [l][0:16 dt | 16:32 B | 32:48 C]
  int bc = blockIdx.x >> 1;
  int d  = ((blockIdx.x & 1) << 8) + threadIdx.x;
  int b = bc >> 8, c = bc & (NCH-1);
  int t0 = b*LL + c*CHUNK;
  int tid = threadIdx.x;
  if (tid < CHUNK*12) {
    int row = tid / 12, q = tid - row*12;
    *(float4*)&DBC[row][q*4] = *(const float4*)&xdbl[(size_t)(t0+row)*XDIM + q*4];
  }
  __syncthreads();
  float4 wq[4];
  #pragma unroll
  for (int i = 0; i < 4; ++i) wq[i] = *(const float4*)&dtw[(size_t)d*RDT + i*4];
  float dtbv = dtb[d];
  float4 cwv = *(const float4*)&cw[d*KC];
  float cbv = cb[d];
  float A[NST];
  #pragma unroll
  for (int n = 0; n < NST; ++n) A[n] = -__expf(A_log[d*NST + n]);
  float A0 = A[0];
  bool geo = true;
  #pragma unroll
  for (int n = 1; n < NST; ++n) {
    float ideal = A0 * (float)(n+1);
    geo = geo && (fabsf(A[n] - ideal) <= 1e-5f * fabsf(ideal));
  }
  float x1 = 0.f, x2 = 0.f, x3 = 0.f;
  if (c > 0) {
    x1 = (float)xm[(size_t)(t0-1)*DI + d];
    x2 = (float)xm[(size_t)(t0-2)*DI + d];
    x3 = (float)xm[(size_t)(t0-3)*DI + d];
  }
  float h[NST];
  #pragma unroll
  for (int n = 0; n < NST; ++n) h[n] = hinit[((size_t)(b*NST + n)*NCH + c)*DI + d];
  float Dpv = Dp[d];
  for (int l = 0; l < CHUNK; ++l) {
    int t = t0 + l;
    float x0 = (float)xm[(size_t)t*DI + d];
    float cv = cbv;
    cv = fmaf(cwv.x, x3, cv); cv = fmaf(cwv.y, x2, cv);
    cv = fmaf(cwv.z, x1, cv); cv = fmaf(cwv.w, x0, cv);
    float xcv = cv * sigmoid_f(cv);
    float acc = dtbv;
    #pragma unroll
    for (int i = 0; i < 4; ++i) {
      float4 a = *(const float4*)&DBC[l][i*4];
      acc = fmaf(a.x, wq[i].x, acc); acc = fmaf(a.y, wq[i].y, acc);
      acc = fmaf(a.z, wq[i].z, acc); acc = fmaf(a.w, wq[i].w, acc);
    }
    float del = fmaxf(acc, 0.f) + log1pf(__expf(-fabsf(acc)));
    float zvg = (float)zg[(size_t)t*DI + d];
    float dx = del * xcv;
    float yv = 0.f;
    if (geo) {
      float e = __expf(del * A0);
      float dA = e;
      h[0] = fmaf(dA, h[0], dx * DBC[l][16]);
      yv = fmaf(h[0], DBC[l][32], yv);
      #pragma unroll
      for (int n = 1; n < NST; ++n) {
        dA *= e;
        h[n] = fmaf(dA, h[n], dx * DBC[l][16 + n]);
        yv = fmaf(h[n], DBC[l][32 + n], yv);
      }
    } else {
      #pragma unroll
      for (int n = 0; n < NST; ++n) {
        h[n] = fmaf(__expf(del * A[n]), h[n], dx * DBC[l][16 + n]);
        yv = fmaf(h[n], DBC[l][32 + n], yv);
      }
    }
    yv = fmaf(Dpv, xcv, yv);
    y[(size_t)t*DI + d] = (__bf16)(yv * zvg);
    x3 = x2; x2 = x1; x1 = x0;
  }
}

// ---------------- pool stage 1: partial sums over L (256 blocks) ----------------
__global__ void pool1_kernel(const float* __restrict__ ln, float* __restrict__ part) {
  int blk = blockIdx.x;             // b*128 + c
  int b = blk >> 7, c = blk & 127;
  int d = threadIdx.x;
  const float* base = ln + (size_t)b*LL*DM + (size_t)c*16*DM + d;
  float s = 0.f;
  #pragma unroll
  for (int l = 0; l < 16; ++l) s += base[(size_t)l*DM];
  part[(size_t)blk*DM + d] = s;
}

// ---------------- pool stage 2 + decode ----------------
__global__ void pool_decode_kernel(const float* __restrict__ part, const float* __restrict__ dw,
                                   const float* __restrict__ db, float* __restrict__ out) {
  int b = blockIdx.x, d = threadIdx.x;
  __shared__ float pooled[DM];
  float s = 0.f;
  for (int c = 0; c < 128; ++c) s += part[(size_t)(b*128 + c)*DM + d];
  pooled[d] = s * (1.0f/LL);
  __syncthreads();
  if (d < DOUT) {
    float acc = db[d];
    for (int m = 0; m < DM; ++m) acc = fmaf(pooled[m], dw[d*DM + m], acc);
    out[b*DOUT + d] = acc;
  }
}

extern "C" void kernel_launch(void* const* d_in, const int* in_sizes, int n_in,
                              void* d_out, int out_size, void* d_ws, size_t ws_size,
                              hipStream_t stream) {
  const int*   ids     = (const int*)d_in[0];
  const float* emb     = (const float*)d_in[1];
  const float* norm_w  = (const float*)d_in[2];
  const float* norm_b  = (const float*)d_in[3];
  const float* in_w    = (const float*)d_in[4];
  const float* conv_w  = (const float*)d_in[5];
  const float* conv_b  = (const float*)d_in[6];
  const float* xp_w    = (const float*)d_in[7];
  const float* dt_w    = (const float*)d_in[8];
  const float* dt_b    = (const float*)d_in[9];
  const float* A_log   = (const float*)d_in[10];
  const float* Dp      = (const float*)d_in[11];
  const float* out_w   = (const float*)d_in[12];
  const float* normf_w = (const float*)d_in[13];
  const float* normf_b = (const float*)d_in[14];
  const float* dec_w   = (const float*)d_in[15];
  const float* dec_b   = (const float*)d_in[16];
  float* out = (float*)d_out;

  float* ws = (float*)d_ws;
  float* hidden   = ws; ws += TOK*DM;
  float* residual = ws; ws += TOK*DM;
  float* hbuf     = ws; ws += TOK*DM;
  float* xdblbuf  = ws; ws += TOK*XDIM;
  float* hlocbuf  = ws; ws += (size_t)BB*NCH*NST*DI;
  float* hinitbuf = ws; ws += (size_t)BB*NCH*NST*DI;
  float* dsumbuf  = ws; ws += (size_t)BB*NCH*DI;
  float* partbuf  = ws; ws += (size_t)BB*128*DM;
  __bf16* xmbuf   = (__bf16*)ws; ws += TOK*DI/2;
  __bf16* zgbuf   = (__bf16*)ws; ws += TOK*DI/2;
  __bf16* hbuf_bf = (__bf16*)ws; ws += TOK*DM/2;
  __bf16* ybuf_bf = (__bf16*)ws; ws += TOK*DI/2;
  __bf16* inw_bf  = (__bf16*)ws; ws += (size_t)NLAY*2*DI*DM/2;
  __bf16* outw_bf = (__bf16*)ws; ws += (size_t)NLAY*DM*DI/2;

  const int n_inw = NLAY*2*DI*DM, n_outw = NLAY*DM*DI;
  cast_w_kernel<<<2048, 256, 0, stream>>>(in_w, out_w, inw_bf, outw_bf, n_inw, n_outw);

  for (int i = 0; i < NLAY; ++i) {
    add_ln_kernel<<<TOK, DM, 0, stream>>>(residual, hidden, ids, emb,
                                          norm_w + i*DM, norm_b + i*DM,
                                          hbuf, hbuf_bf, i == 0, 0);
    gemm_in_bf16<<<dim3((2*DI)/128, TOK/64), 256, 0, stream>>>(
        hbuf_bf, inw_bf + (size_t)i*2*DI*DM, xmbuf, zgbuf);
    xproj_conv<<<TOK/32, 256, 0, stream>>>(
        xmbuf, conv_w + i*DI*KC, conv_b + i*DI, xp_w + (size_t)i*XDIM*DI, xdblbuf);
    scan_pass1<<<BB*NCH*(DI/256), 256, 0, stream>>>(
        xmbuf, xdblbuf, conv_w + i*DI*KC, conv_b + i*DI,
        dt_w + (size_t)i*DI*RDT, dt_b + i*DI, A_log + (size_t)i*DI*NST,
        hlocbuf, dsumbuf);
    scan_pass2<<<(BB*NST*DI)/256, 256, 0, stream>>>(
        hlocbuf, dsumbuf, A_log + (size_t)i*DI*NST, hinitbuf);
    scan_pass3<<<BB*NCH*(DI/256), 256, 0, stream>>>(
        xmbuf, xdblbuf, zgbuf, conv_w + i*DI*KC, conv_b + i*DI,
        dt_w + (size_t)i*DI*RDT, dt_b + i*DI, A_log + (size_t)i*DI*NST,
        Dp + i*DI, hinitbuf, ybuf_bf);
    gemm_out_bf16<<<dim3(DM/64, TOK/64), 256, 0, stream>>>(
        ybuf_bf, outw_bf + (size_t)i*DM*DI, hidden);
  }

  add_ln_kernel<<<TOK, DM, 0, stream>>>(residual, hidden, ids, emb,
                                        normf_w, normf_b, hbuf, hbuf_bf, 0, 1);
  pool1_kernel<<<BB*128, DM, 0, stream>>>(hbuf, partbuf);
  pool_decode_kernel<<<BB, DM, 0, stream>>>(partbuf, dec_w, dec_b, out);
}

// Round 16
// 505.674 us; speedup vs baseline: 1.1050x; 1.1050x over previous
//
#include <hip/hip_runtime.h>
#include <hip/hip_bf16.h>

#define BB 2
#define LL 2048
#define DM 256
#define DI 512
#define NST 16
#define RDT 16
#define KC 4
#define NLAY 4
#define DOUT 10
#define XDIM 48            // R + 2N
#define TOK (BB*LL)        // 4096
#define EPSF 1e-5f
#define CHUNK 16
#define NCH (LL/CHUNK)     // 128

typedef __bf16 bf16x8 __attribute__((ext_vector_type(8)));
typedef __bf16 bf16x4 __attribute__((ext_vector_type(4)));
typedef float  f32x4  __attribute__((ext_vector_type(4)));

__device__ __forceinline__ float sigmoid_f(float x) { return 1.0f / (1.0f + __expf(-x)); }

// ---------------- weight cast fp32 -> bf16 (once per call) ----------------
__global__ void cast_w_kernel(const float* __restrict__ a, const float* __restrict__ b,
                              __bf16* __restrict__ ab, __bf16* __restrict__ bb,
                              int na, int nb) {
  int stride = gridDim.x * 256;
  for (int i = blockIdx.x*256 + threadIdx.x; i < na; i += stride) ab[i] = (__bf16)a[i];
  for (int i = blockIdx.x*256 + threadIdx.x; i < nb; i += stride) bb[i] = (__bf16)b[i];
}

// ------- residual add + layernorm; first layer reads embedding directly -------
__global__ void add_ln_kernel(float* __restrict__ residual, const float* __restrict__ hidden,
                              const int* __restrict__ ids, const float* __restrict__ emb,
                              const float* __restrict__ w, const float* __restrict__ bia,
                              float* __restrict__ out, __bf16* __restrict__ out_bf,
                              int first, int write32) {
  int t = blockIdx.x, d = threadIdx.x;
  __shared__ float ws8[8];
  float r;
  if (first) r = emb[ids[t]*DM + d];
  else       r = hidden[t*DM + d] + residual[t*DM + d];
  residual[t*DM + d] = r;
  float s = r;
  #pragma unroll
  for (int o = 32; o; o >>= 1) s += __shfl_down(s, o);
  if ((d & 63) == 0) ws8[d >> 6] = s;
  __syncthreads();
  float mean = (ws8[0] + ws8[1] + ws8[2] + ws8[3]) * (1.0f/DM);
  float diff = r - mean;
  float q = diff * diff;
  #pragma unroll
  for (int o = 32; o; o >>= 1) q += __shfl_down(q, o);
  if ((d & 63) == 0) ws8[4 + (d >> 6)] = q;
  __syncthreads();
  float var = (ws8[4] + ws8[5] + ws8[6] + ws8[7]) * (1.0f/DM);
  float v = diff * rsqrtf(var + EPSF) * w[d] + bia[d];
  if (write32) out[t*DM + d] = v;
  out_bf[t*DM + d] = (__bf16)v;
}

// ---------------- bf16 MFMA GEMM (in_proj): tile M=64, E=128 ----------------
// cols<512 -> xm bf16; cols>=512 -> zg = silu(z) bf16.
__global__ __launch_bounds__(256, 2) void gemm_in_bf16(const __bf16* __restrict__ A,
                                                       const __bf16* __restrict__ W,
                                                       __bf16* __restrict__ xm,
                                                       __bf16* __restrict__ zg) {
  __shared__ __bf16 As[4*64*8];
  __shared__ __bf16 Ws[8*64*8];
  const int K = DM;
  int tid = threadIdx.x;
  int lane = tid & 63, wv = tid >> 6;
  int bm = blockIdx.y * 64, be = blockIdx.x * 128;
  int ss = tid >> 6, sq = (tid >> 4) & 3, sm = tid & 15;
  f32x4 acc[8];
  #pragma unroll
  for (int et = 0; et < 8; ++et) acc[et] = (f32x4){0.f, 0.f, 0.f, 0.f};
  for (int k0 = 0; k0 < K; k0 += 32) {
    bf16x8 av = *(const bf16x8*)&A[(size_t)(bm + ss*16 + sm)*K + k0 + sq*8];
    bf16x8 w0 = *(const bf16x8*)&W[(size_t)(be + ss*16 + sm)*K + k0 + sq*8];
    bf16x8 w1 = *(const bf16x8*)&W[(size_t)(be + 64 + ss*16 + sm)*K + k0 + sq*8];
    __syncthreads();
    *(bf16x8*)&As[((ss*4 + sq)*16 + sm)*8] = av;
    *(bf16x8*)&Ws[((ss*4 + sq)*16 + sm)*8] = w0;
    *(bf16x8*)&Ws[(((4 + ss)*4 + sq)*16 + sm)*8] = w1;
    __syncthreads();
    bf16x8 af = *(const bf16x8*)&As[(wv*64 + lane)*8];
    #pragma unroll
    for (int et = 0; et < 8; ++et) {
      bf16x8 bfr = *(const bf16x8*)&Ws[(et*64 + lane)*8];
      acc[et] = __builtin_amdgcn_mfma_f32_16x16x32_bf16(af, bfr, acc[et], 0, 0, 0);
    }
  }
  int row0 = bm + wv*16 + (lane >> 4)*4;
  int colb = lane & 15;
  #pragma unroll
  for (int et = 0; et < 8; ++et) {
    int col = be + et*16 + colb;
    if (col < DI) {
      #pragma unroll
      for (int r = 0; r < 4; ++r)
        xm[(size_t)(row0 + r)*DI + col] = (__bf16)acc[et][r];
    } else {
      #pragma unroll
      for (int r = 0; r < 4; ++r) {
        float zv = acc[et][r];
        zg[(size_t)(row0 + r)*DI + col - DI] = (__bf16)(zv * sigmoid_f(zv));
      }
    }
  }
}

// ---------------- bf16 MFMA GEMM (out_proj): tile M=64, E=64, fp32 C ----------------
__global__ __launch_bounds__(256, 2) void gemm_out_bf16(const __bf16* __restrict__ A,
                                                        const __bf16* __restrict__ W,
                                                        float* __restrict__ C) {
  __shared__ __bf16 As[4*64*8];
  __shared__ __bf16 Ws[4*64*8];
  const int K = DI, E = DM;
  int tid = threadIdx.x;
  int lane = tid & 63, wv = tid >> 6;
  int bm = blockIdx.y * 64, be = blockIdx.x * 64;
  int ss = tid >> 6, sq = (tid >> 4) & 3, sm = tid & 15;
  f32x4 acc[4];
  #pragma unroll
  for (int et = 0; et < 4; ++et) acc[et] = (f32x4){0.f, 0.f, 0.f, 0.f};
  for (int k0 = 0; k0 < K; k0 += 32) {
    bf16x8 av = *(const bf16x8*)&A[(size_t)(bm + ss*16 + sm)*K + k0 + sq*8];
    bf16x8 wvv = *(const bf16x8*)&W[(size_t)(be + ss*16 + sm)*K + k0 + sq*8];
    __syncthreads();
    *(bf16x8*)&As[((ss*4 + sq)*16 + sm)*8] = av;
    *(bf16x8*)&Ws[((ss*4 + sq)*16 + sm)*8] = wvv;
    __syncthreads();
    bf16x8 af = *(const bf16x8*)&As[(wv*64 + lane)*8];
    #pragma unroll
    for (int et = 0; et < 4; ++et) {
      bf16x8 bfr = *(const bf16x8*)&Ws[(et*64 + lane)*8];
      acc[et] = __builtin_amdgcn_mfma_f32_16x16x32_bf16(af, bfr, acc[et], 0, 0, 0);
    }
  }
  int row0 = bm + wv*16 + (lane >> 4)*4;
  int col0 = be + (lane & 15);
  #pragma unroll
  for (int et = 0; et < 4; ++et)
    #pragma unroll
    for (int r = 0; r < 4; ++r)
      C[(size_t)(row0 + r)*E + col0 + et*16] = acc[et][r];
}

// ------- x_proj with inline conv+silu: M-tile 32 (128 blocks), E=48 -------
__global__ __launch_bounds__(256) void xproj_conv(const __bf16* __restrict__ xm,
                                                  const float* __restrict__ cw,
                                                  const float* __restrict__ cb,
                                                  const float* __restrict__ W,
                                                  float* __restrict__ out) {
  __shared__ float Xs[32][36];
  __shared__ float Ws[48][36];
  int tid = threadIdx.x;
  int tx = tid & 15, ty = tid >> 4;
  int e0 = tx * 3, t0 = ty * 2;
  int bm = blockIdx.x * 32;
  int xr = tid >> 3, xco = (tid & 7) * 4;       // X staging: 32 rows x 8 quads
  int we = tid >> 2, lc = (tid & 3) * 8;        // W staging: 48 rows x 32 cols
  int tt = bm + xr;
  int l = tt & (LL-1);
  float acc[2][3] = {};
  for (int k0 = 0; k0 < DI; k0 += 32) {
    int ch = k0 + xco;
    bf16x4 v0 = *(const bf16x4*)&xm[(size_t)tt*DI + ch];
    bf16x4 v1 = (l >= 1) ? *(const bf16x4*)&xm[(size_t)(tt-1)*DI + ch] : (bf16x4){0,0,0,0};
    bf16x4 v2 = (l >= 2) ? *(const bf16x4*)&xm[(size_t)(tt-2)*DI + ch] : (bf16x4){0,0,0,0};
    bf16x4 v3 = (l >= 3) ? *(const bf16x4*)&xm[(size_t)(tt-3)*DI + ch] : (bf16x4){0,0,0,0};
    float4 cbv = *(const float4*)&cb[ch];
    float xc4[4];
    #pragma unroll
    for (int j = 0; j < 4; ++j) {
      float4 cwv = *(const float4*)&cw[(ch + j)*KC];
      float cv = ((const float*)&cbv)[j];
      cv = fmaf(cwv.x, (float)v3[j], cv);
      cv = fmaf(cwv.y, (float)v2[j], cv);
      cv = fmaf(cwv.z, (float)v1[j], cv);
      cv = fmaf(cwv.w, (float)v0[j], cv);
      xc4[j] = cv * sigmoid_f(cv);
    }
    *(float4*)&Xs[xr][xco] = make_float4(xc4[0], xc4[1], xc4[2], xc4[3]);
    if (we < 48) {
      float4 w0 = *(const float4*)&W[(size_t)we*DI + k0 + lc];
      float4 w1 = *(const float4*)&W[(size_t)we*DI + k0 + lc + 4];
      *(float4*)&Ws[we][lc]     = w0;
      *(float4*)&Ws[we][lc + 4] = w1;
    }
    __syncthreads();
    #pragma unroll
    for (int kk = 0; kk < 32; kk += 4) {
      float4 xv[2], wv[3];
      #pragma unroll
      for (int i = 0; i < 2; ++i) xv[i] = *(const float4*)&Xs[t0+i][kk];
      #pragma unroll
      for (int j = 0; j < 3; ++j) wv[j] = *(const float4*)&Ws[e0+j][kk];
      #pragma unroll
      for (int i = 0; i < 2; ++i)
        #pragma unroll
        for (int j = 0; j < 3; ++j) {
          acc[i][j] = fmaf(xv[i].x, wv[j].x, acc[i][j]);
          acc[i][j] = fmaf(xv[i].y, wv[j].y, acc[i][j]);
          acc[i][j] = fmaf(xv[i].z, wv[j].z, acc[i][j]);
          acc[i][j] = fmaf(xv[i].w, wv[j].w, acc[i][j]);
        }
    }
    __syncthreads();
  }
  #pragma unroll
  for (int i = 0; i < 2; ++i)
    #pragma unroll
    for (int j = 0; j < 3; ++j)
      out[(size_t)(bm + t0 + i)*XDIM + e0 + j] = acc[i][j];
}

// ---------------- chunked selective scan, conv inline (CHUNK=16, 512 blocks) -------
// hloc/hinit layout: ((b*NST + n)*NCH + c)*DI + d
// pass1 additionally emits ylocal = C.h_loc + Dp*xc and cs = cumsum(delta) per step,
// so pass3 is fully parallel: y = (ylocal + C.G.hinit)*zg with G = exp(A*cs).
__global__ __launch_bounds__(256) void scan_pass1(
    const __bf16* __restrict__ xm, const float* __restrict__ xdbl,
    const float* __restrict__ cw, const float* __restrict__ cb,
    const float* __restrict__ dtw, const float* __restrict__ dtb,
    const float* __restrict__ A_log, const float* __restrict__ Dp,
    float* __restrict__ hloc, float* __restrict__ dsum,
    float* __restrict__ ylocal, float* __restrict__ csout) {
  __shared__ __align__(16) float DBC[CHUNK][48];  // [l][0:16 dt | 16:32 B | 32:48 C]
  int bc = blockIdx.x >> 1;                       // b*NCH + c
  int d  = ((blockIdx.x & 1) << 8) + threadIdx.x;
  int b = bc >> 7, c = bc & (NCH-1);
  int t0 = b*LL + c*CHUNK;
  int tid = threadIdx.x;
  if (tid < CHUNK*12) {
    int row = tid / 12, q = tid - row*12;
    *(float4*)&DBC[row][q*4] = *(const float4*)&xdbl[(size_t)(t0+row)*XDIM + q*4];
  }
  __syncthreads();
  float4 wq[4];
  #pragma unroll
  for (int i = 0; i < 4; ++i) wq[i] = *(const float4*)&dtw[(size_t)d*RDT + i*4];
  float dtbv = dtb[d];
  float4 cwv = *(const float4*)&cw[d*KC];
  float cbv = cb[d];
  float Dpv = Dp[d];
  float A[NST];
  #pragma unroll
  for (int n = 0; n < NST; ++n) A[n] = -__expf(A_log[d*NST + n]);
  float A0 = A[0];
  bool geo = true;
  #pragma unroll
  for (int n = 1; n < NST; ++n) {
    float ideal = A0 * (float)(n+1);
    geo = geo && (fabsf(A[n] - ideal) <= 1e-5f * fabsf(ideal));
  }
  float x1 = 0.f, x2 = 0.f, x3 = 0.f;
  if (c > 0) {
    x1 = (float)xm[(size_t)(t0-1)*DI + d];
    x2 = (float)xm[(size_t)(t0-2)*DI + d];
    x3 = (float)xm[(size_t)(t0-3)*DI + d];
  }
  float h[NST];
  #pragma unroll
  for (int n = 0; n < NST; ++n) h[n] = 0.f;
  float ds = 0.f;
  for (int l = 0; l < CHUNK; ++l) {
    int t = t0 + l;
    float x0 = (float)xm[(size_t)t*DI + d];
    float cv = cbv;
    cv = fmaf(cwv.x, x3, cv); cv = fmaf(cwv.y, x2, cv);
    cv = fmaf(cwv.z, x1, cv); cv = fmaf(cwv.w, x0, cv);
    float xcv = cv * sigmoid_f(cv);
    float acc = dtbv;
    #pragma unroll
    for (int i = 0; i < 4; ++i) {
      float4 a = *(const float4*)&DBC[l][i*4];
      acc = fmaf(a.x, wq[i].x, acc); acc = fmaf(a.y, wq[i].y, acc);
      acc = fmaf(a.z, wq[i].z, acc); acc = fmaf(a.w, wq[i].w, acc);
    }
    float del = fmaxf(acc, 0.f) + log1pf(__expf(-fabsf(acc)));
    ds += del;
    float dx = del * xcv;
    float yv = 0.f;
    if (geo) {
      float e = __expf(del * A0);
      float dA = e;
      h[0] = fmaf(dA, h[0], dx * DBC[l][16]);
      yv = fmaf(h[0], DBC[l][32], yv);
      #pragma unroll
      for (int n = 1; n < NST; ++n) {
        dA *= e;
        h[n] = fmaf(dA, h[n], dx * DBC[l][16 + n]);
        yv = fmaf(h[n], DBC[l][32 + n], yv);
      }
    } else {
      #pragma unroll
      for (int n = 0; n < NST; ++n) {
        h[n] = fmaf(__expf(del * A[n]), h[n], dx * DBC[l][16 + n]);
        yv = fmaf(h[n], DBC[l][32 + n], yv);
      }
    }
    yv = fmaf(Dpv, xcv, yv);
    ylocal[(size_t)t*DI + d] = yv;
    csout[(size_t)t*DI + d] = ds;
    x3 = x2; x2 = x1; x1 = x0;
  }
  #pragma unroll
  for (int n = 0; n < NST; ++n)
    hloc[((size_t)(b*NST + n)*NCH + c)*DI + d] = h[n];
  dsum[(size_t)bc*DI + d] = ds;
}

__global__ __launch_bounds__(256) void scan_pass2(
    const float* __restrict__ hloc, const float* __restrict__ dsum,
    const float* __restrict__ A_log, float* __restrict__ hinit) {
  int g = blockIdx.x*256 + threadIdx.x;
  int d = g & (DI-1);
  int n = (g >> 9) & (NST-1);
  int b = g >> 13;
  float A = -__expf(A_log[d*NST + n]);
  float hc = 0.f;
  size_t base = (size_t)(b*NST + n)*NCH*DI + d;
  for (int c = 0; c < NCH; ++c) {
    hinit[base + (size_t)c*DI] = hc;
    float P = __expf(A * dsum[(size_t)(b*NCH + c)*DI + d]);
    hc = fmaf(P, hc, hloc[base + (size_t)c*DI]);
  }
}

// pass3: fully parallel correction + gate.  y = (ylocal + sum_n C*G*hinit)*zg.
__global__ __launch_bounds__(256) void scan_pass3(
    const float* __restrict__ cs, const float* __restrict__ ylocal,
    const __bf16* __restrict__ zg, const float* __restrict__ xdbl,
    const float* __restrict__ A_log, const float* __restrict__ hinit,
    __bf16* __restrict__ y) {
  __shared__ __align__(16) float Cs[CHUNK][16];
  int bc = blockIdx.x >> 1;
  int d  = ((blockIdx.x & 1) << 8) + threadIdx.x;
  int b = bc >> 7, c = bc & (NCH-1);
  int t0 = b*LL + c*CHUNK;
  int tid = threadIdx.x;
  if (tid < CHUNK*4) {
    int row = tid >> 2, q = tid & 3;
    *(float4*)&Cs[row][q*4] = *(const float4*)&xdbl[(size_t)(t0+row)*XDIM + 32 + q*4];
  }
  __syncthreads();
  float A[NST];
  #pragma unroll
  for (int n = 0; n < NST; ++n) A[n] = -__expf(A_log[d*NST + n]);
  float A0 = A[0];
  bool geo = true;
  #pragma unroll
  for (int n = 1; n < NST; ++n) {
    float ideal = A0 * (float)(n+1);
    geo = geo && (fabsf(A[n] - ideal) <= 1e-5f * fabsf(ideal));
  }
  float hin[NST];
  #pragma unroll
  for (int n = 0; n < NST; ++n) hin[n] = hinit[((size_t)(b*NST + n)*NCH + c)*DI + d];
  for (int l = 0; l < CHUNK; ++l) {
    int t = t0 + l;
    float csv = cs[(size_t)t*DI + d];
    float ylv = ylocal[(size_t)t*DI + d];
    float zvg = (float)zg[(size_t)t*DI + d];
    float corr = 0.f;
    if (geo) {
      float g = __expf(csv * A0);
      float dA = g;
      corr = hin[0] * dA * Cs[l][0];
      #pragma unroll
      for (int n = 1; n < NST; ++n) {
        dA *= g;
        corr = fmaf(hin[n] * dA, Cs[l][n], corr);
      }
    } else {
      #pragma unroll
      for (int n = 0; n < NST; ++n)
        corr = fmaf(hin[n] * __expf(A[n] * csv), Cs[l][n], corr);
    }
    y[(size_t)t*DI + d] = (__bf16)((ylv + corr) * zvg);
  }
}

// ---------------- pool stage 1: partial sums over L (256 blocks) ----------------
__global__ void pool1_kernel(const float* __restrict__ ln, float* __restrict__ part) {
  int blk = blockIdx.x;             // b*128 + c
  int b = blk >> 7, c = blk & 127;
  int d = threadIdx.x;
  const float* base = ln + (size_t)b*LL*DM + (size_t)c*16*DM + d;
  float s = 0.f;
  #pragma unroll
  for (int l = 0; l < 16; ++l) s += base[(size_t)l*DM];
  part[(size_t)blk*DM + d] = s;
}

// ---------------- pool stage 2 + decode ----------------
__global__ void pool_decode_kernel(const float* __restrict__ part, const float* __restrict__ dw,
                                   const float* __restrict__ db, float* __restrict__ out) {
  int b = blockIdx.x, d = threadIdx.x;
  __shared__ float pooled[DM];
  float s = 0.f;
  for (int c = 0; c < 128; ++c) s += part[(size_t)(b*128 + c)*DM + d];
  pooled[d] = s * (1.0f/LL);
  __syncthreads();
  if (d < DOUT) {
    float acc = db[d];
    for (int m = 0; m < DM; ++m) acc = fmaf(pooled[m], dw[d*DM + m], acc);
    out[b*DOUT + d] = acc;
  }
}

extern "C" void kernel_launch(void* const* d_in, const int* in_sizes, int n_in,
                              void* d_out, int out_size, void* d_ws, size_t ws_size,
                              hipStream_t stream) {
  const int*   ids     = (const int*)d_in[0];
  const float* emb     = (const float*)d_in[1];
  const float* norm_w  = (const float*)d_in[2];
  const float* norm_b  = (const float*)d_in[3];
  const float* in_w    = (const float*)d_in[4];
  const float* conv_w  = (const float*)d_in[5];
  const float* conv_b  = (const float*)d_in[6];
  const float* xp_w    = (const float*)d_in[7];
  const float* dt_w    = (const float*)d_in[8];
  const float* dt_b    = (const float*)d_in[9];
  const float* A_log   = (const float*)d_in[10];
  const float* Dp      = (const float*)d_in[11];
  const float* out_w   = (const float*)d_in[12];
  const float* normf_w = (const float*)d_in[13];
  const float* normf_b = (const float*)d_in[14];
  const float* dec_w   = (const float*)d_in[15];
  const float* dec_b   = (const float*)d_in[16];
  float* out = (float*)d_out;

  float* ws = (float*)d_ws;
  float* hidden   = ws; ws += TOK*DM;
  float* residual = ws; ws += TOK*DM;
  float* hbuf     = ws; ws += TOK*DM;
  float* xdblbuf  = ws; ws += TOK*XDIM;
  float* hlocbuf  = ws; ws += (size_t)BB*NCH*NST*DI;
  float* hinitbuf = ws; ws += (size_t)BB*NCH*NST*DI;
  float* dsumbuf  = ws; ws += (size_t)BB*NCH*DI;
  float* partbuf  = ws; ws += (size_t)BB*128*DM;
  float* csbuf    = ws; ws += (size_t)TOK*DI;
  float* ylbuf    = ws; ws += (size_t)TOK*DI;
  __bf16* xmbuf   = (__bf16*)ws; ws += TOK*DI/2;
  __bf16* zgbuf   = (__bf16*)ws; ws += TOK*DI/2;
  __bf16* hbuf_bf = (__bf16*)ws; ws += TOK*DM/2;
  __bf16* ybuf_bf = (__bf16*)ws; ws += TOK*DI/2;
  __bf16* inw_bf  = (__bf16*)ws; ws += (size_t)NLAY*2*DI*DM/2;
  __bf16* outw_bf = (__bf16*)ws; ws += (size_t)NLAY*DM*DI/2;

  const int n_inw = NLAY*2*DI*DM, n_outw = NLAY*DM*DI;
  cast_w_kernel<<<2048, 256, 0, stream>>>(in_w, out_w, inw_bf, outw_bf, n_inw, n_outw);

  for (int i = 0; i < NLAY; ++i) {
    add_ln_kernel<<<TOK, DM, 0, stream>>>(residual, hidden, ids, emb,
                                          norm_w + i*DM, norm_b + i*DM,
                                          hbuf, hbuf_bf, i == 0, 0);
    gemm_in_bf16<<<dim3((2*DI)/128, TOK/64), 256, 0, stream>>>(
        hbuf_bf, inw_bf + (size_t)i*2*DI*DM, xmbuf, zgbuf);
    xproj_conv<<<TOK/32, 256, 0, stream>>>(
        xmbuf, conv_w + i*DI*KC, conv_b + i*DI, xp_w + (size_t)i*XDIM*DI, xdblbuf);
    scan_pass1<<<BB*NCH*(DI/256), 256, 0, stream>>>(
        xmbuf, xdblbuf, conv_w + i*DI*KC, conv_b + i*DI,
        dt_w + (size_t)i*DI*RDT, dt_b + i*DI, A_log + (size_t)i*DI*NST,
        Dp + i*DI, hlocbuf, dsumbuf, ylbuf, csbuf);
    scan_pass2<<<(BB*NST*DI)/256, 256, 0, stream>>>(
        hlocbuf, dsumbuf, A_log + (size_t)i*DI*NST, hinitbuf);
    scan_pass3<<<BB*NCH*(DI/256), 256, 0, stream>>>(
        csbuf, ylbuf, zgbuf, xdblbuf, A_log + (size_t)i*DI*NST,
        hinitbuf, ybuf_bf);
    gemm_out_bf16<<<dim3(DM/64, TOK/64), 256, 0, stream>>>(
        ybuf_bf, outw_bf + (size_t)i*DM*DI, hidden);
  }

  add_ln_kernel<<<TOK, DM, 0, stream>>>(residual, hidden, ids, emb,
                                        normf_w, normf_b, hbuf, hbuf_bf, 0, 1);
  pool1_kernel<<<BB*128, DM, 0, stream>>>(hbuf, partbuf);
  pool_decode_kernel<<<BB, DM, 0, stream>>>(partbuf, dec_w, dec_b, out);
}

// Round 17
// 505.180 us; speedup vs baseline: 1.1061x; 1.0010x over previous
//
#include <hip/hip_runtime.h>
#include <hip/hip_bf16.h>

#define BB 2
#define LL 2048
#define DM 256
#define DI 512
#define NST 16
#define RDT 16
#define KC 4
#define NLAY 4
#define DOUT 10
#define XDIM 48            // R + 2N
#define TOK (BB*LL)        // 4096
#define EPSF 1e-5f
#define CHUNK 16
#define NCH (LL/CHUNK)     // 128

typedef __bf16 bf16x8 __attribute__((ext_vector_type(8)));
typedef __bf16 bf16x4 __attribute__((ext_vector_type(4)));
typedef float  f32x4  __attribute__((ext_vector_type(4)));

__device__ __forceinline__ float sigmoid_f(float x) { return 1.0f / (1.0f + __expf(-x)); }

// ---------------- weight cast fp32 -> bf16 (once per call) ----------------
__global__ void cast_w_kernel(const float* __restrict__ a, const float* __restrict__ b,
                              const float* __restrict__ c,
                              __bf16* __restrict__ ab, __bf16* __restrict__ bb,
                              __bf16* __restrict__ cbf,
                              int na, int nb, int nc) {
  int stride = gridDim.x * 256;
  for (int i = blockIdx.x*256 + threadIdx.x; i < na; i += stride) ab[i] = (__bf16)a[i];
  for (int i = blockIdx.x*256 + threadIdx.x; i < nb; i += stride) bb[i] = (__bf16)b[i];
  for (int i = blockIdx.x*256 + threadIdx.x; i < nc; i += stride) cbf[i] = (__bf16)c[i];
}

// ------- residual add + layernorm; first layer reads embedding directly -------
__global__ void add_ln_kernel(float* __restrict__ residual, const float* __restrict__ hidden,
                              const int* __restrict__ ids, const float* __restrict__ emb,
                              const float* __restrict__ w, const float* __restrict__ bia,
                              float* __restrict__ out, __bf16* __restrict__ out_bf,
                              int first, int write32) {
  int t = blockIdx.x, d = threadIdx.x;
  __shared__ float ws8[8];
  float r;
  if (first) r = emb[ids[t]*DM + d];
  else       r = hidden[t*DM + d] + residual[t*DM + d];
  residual[t*DM + d] = r;
  float s = r;
  #pragma unroll
  for (int o = 32; o; o >>= 1) s += __shfl_down(s, o);
  if ((d & 63) == 0) ws8[d >> 6] = s;
  __syncthreads();
  float mean = (ws8[0] + ws8[1] + ws8[2] + ws8[3]) * (1.0f/DM);
  float diff = r - mean;
  float q = diff * diff;
  #pragma unroll
  for (int o = 32; o; o >>= 1) q += __shfl_down(q, o);
  if ((d & 63) == 0) ws8[4 + (d >> 6)] = q;
  __syncthreads();
  float var = (ws8[4] + ws8[5] + ws8[6] + ws8[7]) * (1.0f/DM);
  float v = diff * rsqrtf(var + EPSF) * w[d] + bia[d];
  if (write32) out[t*DM + d] = v;
  out_bf[t*DM + d] = (__bf16)v;
}

// ---------------- bf16 MFMA GEMM (in_proj): tile M=64, E=128 ----------------
// cols<512 -> xm bf16; cols>=512 -> zg = silu(z) bf16.
__global__ __launch_bounds__(256, 2) void gemm_in_bf16(const __bf16* __restrict__ A,
                                                       const __bf16* __restrict__ W,
                                                       __bf16* __restrict__ xm,
                                                       __bf16* __restrict__ zg) {
  __shared__ __bf16 As[4*64*8];
  __shared__ __bf16 Ws[8*64*8];
  const int K = DM;
  int tid = threadIdx.x;
  int lane = tid & 63, wv = tid >> 6;
  int bm = blockIdx.y * 64, be = blockIdx.x * 128;
  int ss = tid >> 6, sq = (tid >> 4) & 3, sm = tid & 15;
  f32x4 acc[8];
  #pragma unroll
  for (int et = 0; et < 8; ++et) acc[et] = (f32x4){0.f, 0.f, 0.f, 0.f};
  for (int k0 = 0; k0 < K; k0 += 32) {
    bf16x8 av = *(const bf16x8*)&A[(size_t)(bm + ss*16 + sm)*K + k0 + sq*8];
    bf16x8 w0 = *(const bf16x8*)&W[(size_t)(be + ss*16 + sm)*K + k0 + sq*8];
    bf16x8 w1 = *(const bf16x8*)&W[(size_t)(be + 64 + ss*16 + sm)*K + k0 + sq*8];
    __syncthreads();
    *(bf16x8*)&As[((ss*4 + sq)*16 + sm)*8] = av;
    *(bf16x8*)&Ws[((ss*4 + sq)*16 + sm)*8] = w0;
    *(bf16x8*)&Ws[(((4 + ss)*4 + sq)*16 + sm)*8] = w1;
    __syncthreads();
    bf16x8 af = *(const bf16x8*)&As[(wv*64 + lane)*8];
    #pragma unroll
    for (int et = 0; et < 8; ++et) {
      bf16x8 bfr = *(const bf16x8*)&Ws[(et*64 + lane)*8];
      acc[et] = __builtin_amdgcn_mfma_f32_16x16x32_bf16(af, bfr, acc[et], 0, 0, 0);
    }
  }
  int row0 = bm + wv*16 + (lane >> 4)*4;
  int colb = lane & 15;
  #pragma unroll
  for (int et = 0; et < 8; ++et) {
    int col = be + et*16 + colb;
    if (col < DI) {
      #pragma unroll
      for (int r = 0; r < 4; ++r)
        xm[(size_t)(row0 + r)*DI + col] = (__bf16)acc[et][r];
    } else {
      #pragma unroll
      for (int r = 0; r < 4; ++r) {
        float zv = acc[et][r];
        zg[(size_t)(row0 + r)*DI + col - DI] = (__bf16)(zv * sigmoid_f(zv));
      }
    }
  }
}

// ---------------- bf16 MFMA GEMM (out_proj): tile M=64, E=64, fp32 C ----------------
__global__ __launch_bounds__(256, 2) void gemm_out_bf16(const __bf16* __restrict__ A,
                                                        const __bf16* __restrict__ W,
                                                        float* __restrict__ C) {
  __shared__ __bf16 As[4*64*8];
  __shared__ __bf16 Ws[4*64*8];
  const int K = DI, E = DM;
  int tid = threadIdx.x;
  int lane = tid & 63, wv = tid >> 6;
  int bm = blockIdx.y * 64, be = blockIdx.x * 64;
  int ss = tid >> 6, sq = (tid >> 4) & 3, sm = tid & 15;
  f32x4 acc[4];
  #pragma unroll
  for (int et = 0; et < 4; ++et) acc[et] = (f32x4){0.f, 0.f, 0.f, 0.f};
  for (int k0 = 0; k0 < K; k0 += 32) {
    bf16x8 av = *(const bf16x8*)&A[(size_t)(bm + ss*16 + sm)*K + k0 + sq*8];
    bf16x8 wvv = *(const bf16x8*)&W[(size_t)(be + ss*16 + sm)*K + k0 + sq*8];
    __syncthreads();
    *(bf16x8*)&As[((ss*4 + sq)*16 + sm)*8] = av;
    *(bf16x8*)&Ws[((ss*4 + sq)*16 + sm)*8] = wvv;
    __syncthreads();
    bf16x8 af = *(const bf16x8*)&As[(wv*64 + lane)*8];
    #pragma unroll
    for (int et = 0; et < 4; ++et) {
      bf16x8 bfr = *(const bf16x8*)&Ws[(et*64 + lane)*8];
      acc[et] = __builtin_amdgcn_mfma_f32_16x16x32_bf16(af, bfr, acc[et], 0, 0, 0);
    }
  }
  int row0 = bm + wv*16 + (lane >> 4)*4;
  int col0 = be + (lane & 15);
  #pragma unroll
  for (int et = 0; et < 4; ++et)
    #pragma unroll
    for (int r = 0; r < 4; ++r)
      C[(size_t)(row0 + r)*E + col0 + et*16] = acc[et][r];
}

// ------- x_proj via MFMA with conv+silu fused into A-fragment staging -------
// out[t,e] = silu(conv(xm))[t,:] . W[e,:], E=48 (3 subtiles), M-tile 64, grid 64 blocks.
__global__ __launch_bounds__(256, 2) void xproj_mfma(const __bf16* __restrict__ xm,
                                                     const float* __restrict__ cw,
                                                     const float* __restrict__ cb,
                                                     const __bf16* __restrict__ Wbf,
                                                     float* __restrict__ out) {
  __shared__ __bf16 As[4*64*8];
  __shared__ __bf16 Ws[3*64*8];
  int tid = threadIdx.x;
  int lane = tid & 63, wv = tid >> 6;
  int bm = blockIdx.x * 64;
  int ss = tid >> 6, sq = (tid >> 4) & 3, sm = tid & 15;
  int arow = bm + ss*16 + sm;          // token whose fragment this thread stages
  int l = arow & (LL-1);
  f32x4 acc[3];
  #pragma unroll
  for (int e = 0; e < 3; ++e) acc[e] = (f32x4){0.f, 0.f, 0.f, 0.f};
  for (int k0 = 0; k0 < DI; k0 += 32) {
    int ch = k0 + sq*8;
    bf16x8 v0 = *(const bf16x8*)&xm[(size_t)arow*DI + ch];
    bf16x8 v1 = (l >= 1) ? *(const bf16x8*)&xm[(size_t)(arow-1)*DI + ch] : (bf16x8)(__bf16)0;
    bf16x8 v2 = (l >= 2) ? *(const bf16x8*)&xm[(size_t)(arow-2)*DI + ch] : (bf16x8)(__bf16)0;
    bf16x8 v3 = (l >= 3) ? *(const bf16x8*)&xm[(size_t)(arow-3)*DI + ch] : (bf16x8)(__bf16)0;
    __bf16 a8[8];
    #pragma unroll
    for (int j = 0; j < 8; ++j) {
      float4 cwv = *(const float4*)&cw[(ch + j)*KC];
      float cv = cb[ch + j];
      cv = fmaf(cwv.x, (float)v3[j], cv);
      cv = fmaf(cwv.y, (float)v2[j], cv);
      cv = fmaf(cwv.z, (float)v1[j], cv);
      cv = fmaf(cwv.w, (float)v0[j], cv);
      a8[j] = (__bf16)(cv * sigmoid_f(cv));
    }
    bf16x8 w8;
    if (ss < 3) w8 = *(const bf16x8*)&Wbf[(size_t)(ss*16 + sm)*DI + k0 + sq*8];
    __syncthreads();
    #pragma unroll
    for (int j = 0; j < 8; ++j) As[((ss*4 + sq)*16 + sm)*8 + j] = a8[j];
    if (ss < 3) *(bf16x8*)&Ws[((ss*4 + sq)*16 + sm)*8] = w8;
    __syncthreads();
    bf16x8 af = *(const bf16x8*)&As[(wv*64 + lane)*8];
    #pragma unroll
    for (int e = 0; e < 3; ++e) {
      bf16x8 bfr = *(const bf16x8*)&Ws[(e*64 + lane)*8];
      acc[e] = __builtin_amdgcn_mfma_f32_16x16x32_bf16(af, bfr, acc[e], 0, 0, 0);
    }
  }
  int row0 = bm + wv*16 + (lane >> 4)*4;
  int colb = lane & 15;
  #pragma unroll
  for (int e = 0; e < 3; ++e)
    #pragma unroll
    for (int r = 0; r < 4; ++r)
      out[(size_t)(row0 + r)*XDIM + e*16 + colb] = acc[e][r];
}

// ---------------- chunked selective scan, conv inline (CHUNK=16, 512 blocks) -------
// hloc/hinit layout: ((b*NST + n)*NCH + c)*DI + d
// pass1 emits ylocal = C.h_loc + Dp*xc and cs = cumsum(delta); pass3 is fully parallel.
__global__ __launch_bounds__(256) void scan_pass1(
    const __bf16* __restrict__ xm, const float* __restrict__ xdbl,
    const float* __restrict__ cw, const float* __restrict__ cb,
    const float* __restrict__ dtw, const float* __restrict__ dtb,
    const float* __restrict__ A_log, const float* __restrict__ Dp,
    float* __restrict__ hloc, float* __restrict__ dsum,
    float* __restrict__ ylocal, float* __restrict__ csout) {
  __shared__ __align__(16) float DBC[CHUNK][48];  // [l][0:16 dt | 16:32 B | 32:48 C]
  int bc = blockIdx.x >> 1;                       // b*NCH + c
  int d  = ((blockIdx.x & 1) << 8) + threadIdx.x;
  int b = bc >> 7, c = bc & (NCH-1);
  int t0 = b*LL + c*CHUNK;
  int tid = threadIdx.x;
  if (tid < CHUNK*12) {
    int row = tid / 12, q = tid - row*12;
    *(float4*)&DBC[row][q*4] = *(const float4*)&xdbl[(size_t)(t0+row)*XDIM + q*4];
  }
  __syncthreads();
  float4 wq[4];
  #pragma unroll
  for (int i = 0; i < 4; ++i) wq[i] = *(const float4*)&dtw[(size_t)d*RDT + i*4];
  float dtbv = dtb[d];
  float4 cwv = *(const float4*)&cw[d*KC];
  float cbv = cb[d];
  float Dpv = Dp[d];
  float A[NST];
  #pragma unroll
  for (int n = 0; n < NST; ++n) A[n] = -__expf(A_log[d*NST + n]);
  float A0 = A[0];
  bool geo = true;
  #pragma unroll
  for (int n = 1; n < NST; ++n) {
    float ideal = A0 * (float)(n+1);
    geo = geo && (fabsf(A[n] - ideal) <= 1e-5f * fabsf(ideal));
  }
  float x1 = 0.f, x2 = 0.f, x3 = 0.f;
  if (c > 0) {
    x1 = (float)xm[(size_t)(t0-1)*DI + d];
    x2 = (float)xm[(size_t)(t0-2)*DI + d];
    x3 = (float)xm[(size_t)(t0-3)*DI + d];
  }
  float h[NST];
  #pragma unroll
  for (int n = 0; n < NST; ++n) h[n] = 0.f;
  float ds = 0.f;
  for (int l = 0; l < CHUNK; ++l) {
    int t = t0 + l;
    float x0 = (float)xm[(size_t)t*DI + d];
    float cv = cbv;
    cv = fmaf(cwv.x, x3, cv); cv = fmaf(cwv.y, x2, cv);
    cv = fmaf(cwv.z, x1, cv); cv = fmaf(cwv.w, x0, cv);
    float xcv = cv * sigmoid_f(cv);
    float acc = dtbv;
    #pragma unroll
    for (int i = 0; i < 4; ++i) {
      float4 a = *(const float4*)&DBC[l][i*4];
      acc = fmaf(a.x, wq[i].x, acc); acc = fmaf(a.y, wq[i].y, acc);
      acc = fmaf(a.z, wq[i].z, acc); acc = fmaf(a.w, wq[i].w, acc);
    }
    float del = fmaxf(acc, 0.f) + log1pf(__expf(-fabsf(acc)));
    ds += del;
    float dx = del * xcv;
    float yv = 0.f;
    if (geo) {
      float e = __expf(del * A0);
      float dA = e;
      h[0] = fmaf(dA, h[0], dx * DBC[l][16]);
      yv = fmaf(h[0], DBC[l][32], yv);
      #pragma unroll
      for (int n = 1; n < NST; ++n) {
        dA *= e;
        h[n] = fmaf(dA, h[n], dx * DBC[l][16 + n]);
        yv = fmaf(h[n], DBC[l][32 + n], yv);
      }
    } else {
      #pragma unroll
      for (int n = 0; n < NST; ++n) {
        h[n] = fmaf(__expf(del * A[n]), h[n], dx * DBC[l][16 + n]);
        yv = fmaf(h[n], DBC[l][32 + n], yv);
      }
    }
    yv = fmaf(Dpv, xcv, yv);
    ylocal[(size_t)t*DI + d] = yv;
    csout[(size_t)t*DI + d] = ds;
    x3 = x2; x2 = x1; x1 = x0;
  }
  #pragma unroll
  for (int n = 0; n < NST; ++n)
    hloc[((size_t)(b*NST + n)*NCH + c)*DI + d] = h[n];
  dsum[(size_t)bc*DI + d] = ds;
}

__global__ __launch_bounds__(256) void scan_pass2(
    const float* __restrict__ hloc, const float* __restrict__ dsum,
    const float* __restrict__ A_log, float* __restrict__ hinit) {
  int g = blockIdx.x*256 + threadIdx.x;
  int d = g & (DI-1);
  int n = (g >> 9) & (NST-1);
  int b = g >> 13;
  float A = -__expf(A_log[d*NST + n]);
  float hc = 0.f;
  size_t base = (size_t)(b*NST + n)*NCH*DI + d;
  #pragma unroll 4
  for (int c = 0; c < NCH; ++c) {
    hinit[base + (size_t)c*DI] = hc;
    float P = __expf(A * dsum[(size_t)(b*NCH + c)*DI + d]);
    hc = fmaf(P, hc, hloc[base + (size_t)c*DI]);
  }
}

// pass3: fully parallel correction + gate.  y = (ylocal + sum_n C*G*hinit)*zg.
__global__ __launch_bounds__(256) void scan_pass3(
    const float* __restrict__ cs, const float* __restrict__ ylocal,
    const __bf16* __restrict__ zg, const float* __restrict__ xdbl,
    const float* __restrict__ A_log, const float* __restrict__ hinit,
    __bf16* __restrict__ y) {
  __shared__ __align__(16) float Cs[CHUNK][16];
  int bc = blockIdx.x >> 1;
  int d  = ((blockIdx.x & 1) << 8) + threadIdx.x;
  int b = bc >> 7, c = bc & (NCH-1);
  int t0 = b*LL + c*CHUNK;
  int tid = threadIdx.x;
  if (tid < CHUNK*4) {
    int row = tid >> 2, q = tid & 3;
    *(float4*)&Cs[row][q*4] = *(const float4*)&xdbl[(size_t)(t0+row)*XDIM + 32 + q*4];
  }
  __syncthreads();
  float A[NST];
  #pragma unroll
  for (int n = 0; n < NST; ++n) A[n] = -__expf(A_log[d*NST + n]);
  float A0 = A[0];
  bool geo = true;
  #pragma unroll
  for (int n = 1; n < NST; ++n) {
    float ideal = A0 * (float)(n+1);
    geo = geo && (fabsf(A[n] - ideal) <= 1e-5f * fabsf(ideal));
  }
  float hin[NST];
  #pragma unroll
  for (int n = 0; n < NST; ++n) hin[n] = hinit[((size_t)(b*NST + n)*NCH + c)*DI + d];
  for (int l = 0; l < CHUNK; ++l) {
    int t = t0 + l;
    float csv = cs[(size_t)t*DI + d];
    float ylv = ylocal[(size_t)t*DI + d];
    float zvg = (float)zg[(size_t)t*DI + d];
    float corr = 0.f;
    if (geo) {
      float g = __expf(csv * A0);
      float dA = g;
      corr = hin[0] * dA * Cs[l][0];
      #pragma unroll
      for (int n = 1; n < NST; ++n) {
        dA *= g;
        corr = fmaf(hin[n] * dA, Cs[l][n], corr);
      }
    } else {
      #pragma unroll
      for (int n = 0; n < NST; ++n)
        corr = fmaf(hin[n] * __expf(A[n] * csv), Cs[l][n], corr);
    }
    y[(size_t)t*DI + d] = (__bf16)((ylv + corr) * zvg);
  }
}

// ---------------- pool stage 1: partial sums over L (256 blocks) ----------------
__global__ void pool1_kernel(const float* __restrict__ ln, float* __restrict__ part) {
  int blk = blockIdx.x;             // b*128 + c
  int b = blk >> 7, c = blk & 127;
  int d = threadIdx.x;
  const float* base = ln + (size_t)b*LL*DM + (size_t)c*16*DM + d;
  float s = 0.f;
  #pragma unroll
  for (int l = 0; l < 16; ++l) s += base[(size_t)l*DM];
  part[(size_t)blk*DM + d] = s;
}

// ---------------- pool stage 2 + decode ----------------
__global__ void pool_decode_kernel(const float* __restrict__ part, const float* __restrict__ dw,
                                   const float* __restrict__ db, float* __restrict__ out) {
  int b = blockIdx.x, d = threadIdx.x;
  __shared__ float pooled[DM];
  float s = 0.f;
  for (int c = 0; c < 128; ++c) s += part[(size_t)(b*128 + c)*DM + d];
  pooled[d] = s * (1.0f/LL);
  __syncthreads();
  if (d < DOUT) {
    float acc = db[d];
    for (int m = 0; m < DM; ++m) acc = fmaf(pooled[m], dw[d*DM + m], acc);
    out[b*DOUT + d] = acc;
  }
}

extern "C" void kernel_launch(void* const* d_in, const int* in_sizes, int n_in,
                              void* d_out, int out_size, void* d_ws, size_t ws_size,
                              hipStream_t stream) {
  const int*   ids     = (const int*)d_in[0];
  const float* emb     = (const float*)d_in[1];
  const float* norm_w  = (const float*)d_in[2];
  const float* norm_b  = (const float*)d_in[3];
  const float* in_w    = (const float*)d_in[4];
  const float* conv_w  = (const float*)d_in[5];
  const float* conv_b  = (const float*)d_in[6];
  const float* xp_w    = (const float*)d_in[7];
  const float* dt_w    = (const float*)d_in[8];
  const float* dt_b    = (const float*)d_in[9];
  const float* A_log   = (const float*)d_in[10];
  const float* Dp      = (const float*)d_in[11];
  const float* out_w   = (const float*)d_in[12];
  const float* normf_w = (const float*)d_in[13];
  const float* normf_b = (const float*)d_in[14];
  const float* dec_w   = (const float*)d_in[15];
  const float* dec_b   = (const float*)d_in[16];
  float* out = (float*)d_out;

  float* ws = (float*)d_ws;
  float* hidden   = ws; ws += TOK*DM;
  float* residual = ws; ws += TOK*DM;
  float* hbuf     = ws; ws += TOK*DM;
  float* xdblbuf  = ws; ws += TOK*XDIM;
  float* hlocbuf  = ws; ws += (size_t)BB*NCH*NST*DI;
  float* hinitbuf = ws; ws += (size_t)BB*NCH*NST*DI;
  float* dsumbuf  = ws; ws += (size_t)BB*NCH*DI;
  float* partbuf  = ws; ws += (size_t)BB*128*DM;
  float* csbuf    = ws; ws += (size_t)TOK*DI;
  float* ylbuf    = ws; ws += (size_t)TOK*DI;
  __bf16* xmbuf   = (__bf16*)ws; ws += TOK*DI/2;
  __bf16* zgbuf   = (__bf16*)ws; ws += TOK*DI/2;
  __bf16* hbuf_bf = (__bf16*)ws; ws += TOK*DM/2;
  __bf16* ybuf_bf = (__bf16*)ws; ws += TOK*DI/2;
  __bf16* inw_bf  = (__bf16*)ws; ws += (size_t)NLAY*2*DI*DM/2;
  __bf16* outw_bf = (__bf16*)ws; ws += (size_t)NLAY*DM*DI/2;
  __bf16* xpw_bf  = (__bf16*)ws; ws += (size_t)NLAY*XDIM*DI/2 + 256;

  const int n_inw = NLAY*2*DI*DM, n_outw = NLAY*DM*DI, n_xpw = NLAY*XDIM*DI;
  cast_w_kernel<<<2048, 256, 0, stream>>>(in_w, out_w, xp_w, inw_bf, outw_bf, xpw_bf,
                                          n_inw, n_outw, n_xpw);

  for (int i = 0; i < NLAY; ++i) {
    add_ln_kernel<<<TOK, DM, 0, stream>>>(residual, hidden, ids, emb,
                                          norm_w + i*DM, norm_b + i*DM,
                                          hbuf, hbuf_bf, i == 0, 0);
    gemm_in_bf16<<<dim3((2*DI)/128, TOK/64), 256, 0, stream>>>(
        hbuf_bf, inw_bf + (size_t)i*2*DI*DM, xmbuf, zgbuf);
    xproj_mfma<<<TOK/64, 256, 0, stream>>>(
        xmbuf, conv_w + i*DI*KC, conv_b + i*DI,
        xpw_bf + (size_t)i*XDIM*DI, xdblbuf);
    scan_pass1<<<BB*NCH*(DI/256), 256, 0, stream>>>(
        xmbuf, xdblbuf, conv_w + i*DI*KC, conv_b + i*DI,
        dt_w + (size_t)i*DI*RDT, dt_b + i*DI, A_log + (size_t)i*DI*NST,
        Dp + i*DI, hlocbuf, dsumbuf, ylbuf, csbuf);
    scan_pass2<<<(BB*NST*DI)/256, 256, 0, stream>>>(
        hlocbuf, dsumbuf, A_log + (size_t)i*DI*NST, hinitbuf);
    scan_pass3<<<BB*NCH*(DI/256), 256, 0, stream>>>(
        csbuf, ylbuf, zgbuf, xdblbuf, A_log + (size_t)i*DI*NST,
        hinitbuf, ybuf_bf);
    gemm_out_bf16<<<dim3(DM/64, TOK/64), 256, 0, stream>>>(
        ybuf_bf, outw_bf + (size_t)i*DM*DI, hidden);
  }

  add_ln_kernel<<<TOK, DM, 0, stream>>>(residual, hidden, ids, emb,
                                        normf_w, normf_b, hbuf, hbuf_bf, 0, 1);
  pool1_kernel<<<BB*128, DM, 0, stream>>>(hbuf, partbuf);
  pool_decode_kernel<<<BB, DM, 0, stream>>>(partbuf, dec_w, dec_b, out);
}